// Round 1
// baseline (1812.496 us; speedup 1.0000x reference)
//
#include <hip/hip_runtime.h>

// Problem constants: B=16, N=512, T=64, D=64, H=8, K=3, DK=8
// grid = B*N = 8192 blocks, 256 threads (4 waves)

#define OUT_ELEMS 33554432ull   // B*N*T*D
// p elems = B*N*H*T*T = 268435456

// ws layout (floats):
//   WqT [ (c*3+j)*64 + d ]  at 0      (12288)
//   WkT                     at 12288  (12288)
//   WvT [ c*64 + d ]        at 24576  (4096)
//   WoT [ d*64 + dp ]       at 28672  (4096)

__global__ __launch_bounds__(256) void prep_weights(
    const float* __restrict__ Wq, const float* __restrict__ Wk,
    const float* __restrict__ Wv, const float* __restrict__ Wo,
    float* __restrict__ ws) {
  int i = blockIdx.x * 256 + threadIdx.x;
  if (i < 12288) {
    int d = i & 63; int cj = i >> 6; int c = cj / 3; int j = cj - 3 * c;
    ws[i] = Wq[(d * 64 + c) * 3 + j];
  } else if (i < 24576) {
    int t = i - 12288;
    int d = t & 63; int cj = t >> 6; int c = cj / 3; int j = cj - 3 * c;
    ws[i] = Wk[(d * 64 + c) * 3 + j];
  } else if (i < 28672) {
    int t = i - 24576; int d = t & 63; int c = t >> 6;
    ws[i] = Wv[d * 64 + c];
  } else if (i < 32768) {
    int t = i - 28672; int dp = t & 63; int dd = t >> 6;
    ws[i] = Wo[dp * 64 + dd];
  }
}

// conv helper: each thread owns output channel d, 16 consecutive t's (tg*16..+15)
// buf rows: row r = x[r-2] (rows 0,1 are zeros)
__device__ __forceinline__ void conv16(const float* __restrict__ buf,
                                       const float* __restrict__ Wt,
                                       float bias, int d, int tg, float* acc) {
#pragma unroll
  for (int i = 0; i < 16; i++) acc[i] = bias;
#pragma unroll 4
  for (int c = 0; c < 64; c++) {
#pragma unroll
    for (int j = 0; j < 3; j++) {
      float w = Wt[(c * 3 + j) * 64 + d];
#pragma unroll
      for (int i = 0; i < 16; i++)
        acc[i] = fmaf(buf[(tg * 16 + i + j) * 64 + c], w, acc[i]);
    }
  }
}

__global__ __launch_bounds__(256) void fused_attn(
    const float* __restrict__ query, const float* __restrict__ key,
    const float* __restrict__ value, const int* __restrict__ mask,
    const float* __restrict__ ws,
    const float* __restrict__ bq, const float* __restrict__ bk,
    const float* __restrict__ bv, const float* __restrict__ bo,
    float* __restrict__ out, float* __restrict__ p_out) {
  __shared__ float buf[4224];      // input tile [66][64]; later x accum [64][65]
  __shared__ float q_s[4096];      // q [t][d]
  __shared__ float kT[64 * 65];    // k transposed [d][s], pad 65
  __shared__ float v_s[4096];      // v [s][d]
  __shared__ float S[32 * 65];     // p sub-tile [32 rows][s], pad 65

  const int tid = threadIdx.x;
  const int bid = blockIdx.x;      // b*512 + n
  const int b = bid >> 9;
  const int d = tid & 63;          // lane / channel / s
  const int tg = tid >> 6;         // wave id 0..3

  const float* WqT = ws;
  const float* WkT = ws + 12288;
  const float* WvT = ws + 24576;
  const float* WoT = ws + 28672;

  if (tid < 128) buf[tid] = 0.f;   // zero pad rows 0,1

  // ---------------- load query tile ----------------
  {
    const float4* src = (const float4*)(query + (size_t)bid * 4096);
    float4* dst = (float4*)(buf + 128);
#pragma unroll
    for (int i = tid; i < 1024; i += 256) dst[i] = src[i];
  }
  __syncthreads();

  // ---------------- conv q -> q_s[t][d] ----------------
  {
    float acc[16];
    conv16(buf, WqT, bq[d], d, tg, acc);
#pragma unroll
    for (int i = 0; i < 16; i++) q_s[(tg * 16 + i) * 64 + d] = acc[i];
  }
  __syncthreads();

  // ---------------- load key tile ----------------
  {
    const float4* src = (const float4*)(key + (size_t)bid * 4096);
    float4* dst = (float4*)(buf + 128);
#pragma unroll
    for (int i = tid; i < 1024; i += 256) dst[i] = src[i];
  }
  __syncthreads();

  // ---------------- conv k -> kT[d][s] ----------------
  {
    float acc[16];
    conv16(buf, WkT, bk[d], d, tg, acc);
#pragma unroll
    for (int i = 0; i < 16; i++) kT[d * 65 + tg * 16 + i] = acc[i];
  }
  __syncthreads();

  // ---------------- load value tile ----------------
  {
    const float4* src = (const float4*)(value + (size_t)bid * 4096);
    float4* dst = (float4*)(buf + 128);
#pragma unroll
    for (int i = tid; i < 1024; i += 256) dst[i] = src[i];
  }
  __syncthreads();

  // ---------------- v projection -> v_s[s][d] ----------------
  {
    float acc[16];
    float bias = bv[d];
#pragma unroll
    for (int i = 0; i < 16; i++) acc[i] = bias;
#pragma unroll 4
    for (int c = 0; c < 64; c++) {
      float w = WvT[c * 64 + d];
#pragma unroll
      for (int i = 0; i < 16; i++)
        acc[i] = fmaf(buf[(tg * 16 + i + 2) * 64 + c], w, acc[i]);
    }
#pragma unroll
    for (int i = 0; i < 16; i++) v_s[(tg * 16 + i) * 64 + d] = acc[i];
  }
  __syncthreads();

  // ---------------- mask bits for my (s = d) lane, 16 rows ----------------
  unsigned mbits = 0;
  {
#pragma unroll
    for (int th = 0; th < 2; th++)
#pragma unroll
      for (int r = 0; r < 8; r++) {
        int t = th * 32 + tg * 8 + r;
        if (mask[((size_t)b * 64 + t) * 64 + d]) mbits |= (1u << (th * 8 + r));
      }
  }

  float* xbuf = buf;  // reuse as x accum [t*65 + dd]
  const float scale = 0.35355339059327373f;  // 1/sqrt(8)

  // ---------------- attention: per head, per 32-row half ----------------
  for (int h = 0; h < 8; h++) {
#pragma unroll 1
    for (int th = 0; th < 2; th++) {
      // scores + wave softmax + p write + stage S
      {
        const int s = d;
#pragma unroll
        for (int r = 0; r < 8; r++) {
          int t = th * 32 + tg * 8 + r;
          float acc = 0.f;
#pragma unroll
          for (int dk = 0; dk < 8; dk++)
            acc = fmaf(q_s[t * 64 + h * 8 + dk], kT[(h * 8 + dk) * 65 + s], acc);
          float val = ((mbits >> (th * 8 + r)) & 1u) ? acc * scale : -1e9f;
          float m = val;
#pragma unroll
          for (int off = 32; off >= 1; off >>= 1)
            m = fmaxf(m, __shfl_xor(m, off));
          float e = __expf(val - m);
          float sum = e;
#pragma unroll
          for (int off = 32; off >= 1; off >>= 1)
            sum += __shfl_xor(sum, off);
          float pv = e / sum;
          p_out[(((size_t)bid * 8 + h) * 64 + t) * 64 + s] = pv;
          S[(tg * 8 + r) * 65 + s] = pv;
        }
      }
      __syncthreads();
      // PV: x[t][h*8+dk] += sum_s S[t][s] * v[s][h*8+dk]
      {
        const int dk = tid & 7;
        const int tr = tid >> 3;  // 0..31
        float acc = 0.f;
#pragma unroll 8
        for (int s = 0; s < 64; s++)
          acc = fmaf(S[tr * 65 + s], v_s[s * 64 + h * 8 + dk], acc);
        xbuf[(th * 32 + tr) * 65 + h * 8 + dk] = acc;
      }
      __syncthreads();
    }
  }

  // ---------------- output projection ----------------
  {
    const int dp = d;
    float bias = bo[dp];
#pragma unroll
    for (int i = 0; i < 16; i++) {
      int t = tg * 16 + i;
      float acc = bias;
#pragma unroll 8
      for (int c = 0; c < 64; c++)
        acc = fmaf(xbuf[t * 65 + c], WoT[c * 64 + dp], acc);
      out[(size_t)bid * 4096 + t * 64 + dp] = acc;
    }
  }
}

extern "C" void kernel_launch(void* const* d_in, const int* in_sizes, int n_in,
                              void* d_out, int out_size, void* d_ws, size_t ws_size,
                              hipStream_t stream) {
  const float* query = (const float*)d_in[0];
  const float* key   = (const float*)d_in[1];
  const float* value = (const float*)d_in[2];
  // d_in[3] = att (unused)
  const int*   mask  = (const int*)d_in[4];
  const float* Wq = (const float*)d_in[5];
  const float* bq = (const float*)d_in[6];
  const float* Wk = (const float*)d_in[7];
  const float* bk = (const float*)d_in[8];
  const float* Wv = (const float*)d_in[9];
  const float* bv = (const float*)d_in[10];
  const float* Wo = (const float*)d_in[11];
  const float* bo = (const float*)d_in[12];

  float* out = (float*)d_out;
  float* p_out = out + OUT_ELEMS;
  float* ws = (float*)d_ws;

  hipLaunchKernelGGL(prep_weights, dim3(128), dim3(256), 0, stream,
                     Wq, Wk, Wv, Wo, ws);
  hipLaunchKernelGGL(fused_attn, dim3(8192), dim3(256), 0, stream,
                     query, key, value, mask, ws, bq, bk, bv, bo, out, p_out);
}

// Round 2
// 1331.178 us; speedup vs baseline: 1.3616x; 1.3616x over previous
//
#include <hip/hip_runtime.h>

// B=16, N=512, T=64, D=64, H=8, K=3, DK=8
// grid = 8192 blocks (one per (b,n)), 256 threads (4 waves), 3 blocks/CU target

#define OUT_ELEMS 33554432ull   // B*N*T*D

typedef unsigned short ushort_t;
typedef unsigned int uint_t;

// ws float layout: Wq4[12288] | Wk4[12288] | Wv4[4096] | Wo4[4096]
// Wq4/Wk4: float4 idx (c4*3+j)*64+d holds W[d][c4*4+e][j] for e=0..3
// Wv4:     float4 idx  c4*64+d     holds Wv[d][c4*4+e]
// Wo4:     float4 idx  c4*64+dp    holds Wo[dp][c4*4+e]

__global__ __launch_bounds__(256) void prep_weights(
    const float* __restrict__ Wq, const float* __restrict__ Wk,
    const float* __restrict__ Wv, const float* __restrict__ Wo,
    float* __restrict__ ws) {
  int i = blockIdx.x * 256 + threadIdx.x;
  if (i < 12288) {
    int e = i & 3; int q = i >> 2; int d = q & 63; int cj = q >> 6;
    int c4 = cj / 3; int j = cj - 3 * c4;
    ws[i] = Wq[(d * 64 + c4 * 4 + e) * 3 + j];
  } else if (i < 24576) {
    int t = i - 12288;
    int e = t & 3; int q = t >> 2; int d = q & 63; int cj = q >> 6;
    int c4 = cj / 3; int j = cj - 3 * c4;
    ws[i] = Wk[(d * 64 + c4 * 4 + e) * 3 + j];
  } else if (i < 28672) {
    int t = i - 24576; int e = t & 3; int q = t >> 2; int d = q & 63; int c4 = q >> 6;
    ws[i] = Wv[d * 64 + c4 * 4 + e];
  } else if (i < 32768) {
    int t = i - 28672; int e = t & 3; int q = t >> 2; int dp = q & 63; int c4 = q >> 6;
    ws[i] = Wo[dp * 64 + c4 * 4 + e];
  }
}

__device__ __forceinline__ ushort_t f2b(float f) {  // f32 -> bf16 RNE
  uint_t u = __float_as_uint(f);
  return (ushort_t)((u + 0x7fffu + ((u >> 16) & 1u)) >> 16);
}
__device__ __forceinline__ float b2f_lo(uint_t u) { return __uint_as_float(u << 16); }
__device__ __forceinline__ float b2f_hi(uint_t u) { return __uint_as_float(u & 0xffff0000u); }

// causal conv over 16 t's for one output channel d. buf row r = x[r-2] (rows 0,1 zero).
// y[t] = x[t-2]*w0 + x[t-1]*w1 + x[t]*w2  (t = tg*16 + i)
__device__ __forceinline__ void conv16v(const float* __restrict__ bufp,
                                        const float4* __restrict__ W4,
                                        float bias, int d, int tg, float acc[16]) {
#pragma unroll
  for (int i = 0; i < 16; i++) acc[i] = bias;
  const int base = tg * 16;
#pragma unroll 2
  for (int c4 = 0; c4 < 16; c4++) {
    float4 w0 = W4[(c4 * 3 + 0) * 64 + d];
    float4 w1 = W4[(c4 * 3 + 1) * 64 + d];
    float4 w2 = W4[(c4 * 3 + 2) * 64 + d];
#pragma unroll
    for (int row = 0; row < 18; row++) {
      float4 x = *(const float4*)(bufp + (base + row) * 64 + c4 * 4);
      if (row < 16) {
        int i = row;
        acc[i] = fmaf(x.x, w0.x, acc[i]); acc[i] = fmaf(x.y, w0.y, acc[i]);
        acc[i] = fmaf(x.z, w0.z, acc[i]); acc[i] = fmaf(x.w, w0.w, acc[i]);
      }
      if (row >= 1 && row <= 16) {
        int i = row - 1;
        acc[i] = fmaf(x.x, w1.x, acc[i]); acc[i] = fmaf(x.y, w1.y, acc[i]);
        acc[i] = fmaf(x.z, w1.z, acc[i]); acc[i] = fmaf(x.w, w1.w, acc[i]);
      }
      if (row >= 2) {
        int i = row - 2;
        acc[i] = fmaf(x.x, w2.x, acc[i]); acc[i] = fmaf(x.y, w2.y, acc[i]);
        acc[i] = fmaf(x.z, w2.z, acc[i]); acc[i] = fmaf(x.w, w2.w, acc[i]);
      }
    }
  }
}

__global__ __launch_bounds__(256, 3) void fused_attn(
    const float* __restrict__ query, const float* __restrict__ key,
    const float* __restrict__ value, const int* __restrict__ mask,
    const float* __restrict__ ws,
    const float* __restrict__ bq, const float* __restrict__ bk,
    const float* __restrict__ bv, const float* __restrict__ bo,
    float* __restrict__ out, float* __restrict__ p_out) {
  __shared__ float buf[4352];       // conv input [rows<=66][64]; alias S[64][68] in attention
  __shared__ float vT[4352];        // v transposed [d][68]
  __shared__ ushort_t q_b[4096];    // q bf16 [t][64]; slice h becomes x (bf16) after PV-h
  __shared__ ushort_t k_b[4608];    // k bf16 [s][72] (72: b128-aligned, 2-way max)

  const int tid = threadIdx.x;
  const int bid = blockIdx.x;       // b*512 + n
  const int b = bid >> 9;
  const int lane = tid & 63;        // channel d / s-column
  const int tg = tid >> 6;          // wave 0..3

  const float4* Wq4 = (const float4*)ws;
  const float4* Wk4 = (const float4*)(ws + 12288);
  const float4* Wv4 = (const float4*)(ws + 24576);
  const float4* Wo4 = (const float4*)(ws + 28672);

  // ---- load q tile (rows 0,1 zero; row r+2 = x[r]) ----
  if (tid < 32) ((float4*)buf)[tid] = make_float4(0.f, 0.f, 0.f, 0.f);
  {
    const float4* src = (const float4*)(query + (size_t)bid * 4096);
    float4* dst = (float4*)(buf + 128);
#pragma unroll
    for (int i = 0; i < 4; i++) dst[tid + 256 * i] = src[tid + 256 * i];
  }
  __syncthreads();
  // ---- conv q -> q_b ----
  {
    float acc[16];
    conv16v(buf, Wq4, bq[lane], lane, tg, acc);
#pragma unroll
    for (int i = 0; i < 16; i++) q_b[(tg * 16 + i) * 64 + lane] = f2b(acc[i]);
  }
  __syncthreads();
  // ---- load key tile ----
  {
    const float4* src = (const float4*)(key + (size_t)bid * 4096);
    float4* dst = (float4*)(buf + 128);
#pragma unroll
    for (int i = 0; i < 4; i++) dst[tid + 256 * i] = src[tid + 256 * i];
  }
  __syncthreads();
  // ---- conv k -> k_b [s][72] ----
  {
    float acc[16];
    conv16v(buf, Wk4, bk[lane], lane, tg, acc);
#pragma unroll
    for (int i = 0; i < 16; i++) k_b[(tg * 16 + i) * 72 + lane] = f2b(acc[i]);
  }
  __syncthreads();
  // ---- load value tile ----
  {
    const float4* src = (const float4*)(value + (size_t)bid * 4096);
    float4* dst = (float4*)(buf + 128);
#pragma unroll
    for (int i = 0; i < 4; i++) dst[tid + 256 * i] = src[tid + 256 * i];
  }
  __syncthreads();
  // ---- v projection -> vT[d][68] (f32) ----
  {
    float acc[16];
    float bias = bv[lane];
#pragma unroll
    for (int i = 0; i < 16; i++) acc[i] = bias;
    const int base = tg * 16;
#pragma unroll 2
    for (int c4 = 0; c4 < 16; c4++) {
      float4 w = Wv4[c4 * 64 + lane];
#pragma unroll
      for (int i = 0; i < 16; i++) {
        float4 x = *(const float4*)(buf + (base + i + 2) * 64 + c4 * 4);
        acc[i] = fmaf(x.x, w.x, fmaf(x.y, w.y, fmaf(x.z, w.z, fmaf(x.w, w.w, acc[i]))));
      }
    }
#pragma unroll
    for (int i = 0; i < 16; i++) vT[lane * 68 + base + i] = acc[i];
  }

  // ---- mask bits: row t=tg*16+r, col s=lane ----
  unsigned mb = 0;
#pragma unroll
  for (int r = 0; r < 16; r++)
    if (mask[(size_t)b * 4096 + (tg * 16 + r) * 64 + lane]) mb |= 1u << r;
  __syncthreads();   // buf free -> S

  float* S = buf;    // S[64][68]
  const float scale = 0.35355339059327373f;  // 1/sqrt(8)

#pragma unroll 1
  for (int h = 0; h < 8; h++) {
    // ---- scores + softmax + p write + stage S (rows tg*16..+15, col = lane) ----
    uint4 kv = *(const uint4*)(k_b + lane * 72 + h * 8);
    float kf0 = b2f_lo(kv.x), kf1 = b2f_hi(kv.x), kf2 = b2f_lo(kv.y), kf3 = b2f_hi(kv.y);
    float kf4 = b2f_lo(kv.z), kf5 = b2f_hi(kv.z), kf6 = b2f_lo(kv.w), kf7 = b2f_hi(kv.w);
    float* pbase = p_out + ((size_t)bid * 8 + h) * 4096;
#pragma unroll
    for (int g = 0; g < 2; g++) {
      float val[8];
#pragma unroll
      for (int r = 0; r < 8; r++) {
        int t = tg * 16 + g * 8 + r;
        uint4 qv = *(const uint4*)(q_b + t * 64 + h * 8);
        float a = b2f_lo(qv.x) * kf0;
        a = fmaf(b2f_hi(qv.x), kf1, a);
        a = fmaf(b2f_lo(qv.y), kf2, a);
        a = fmaf(b2f_hi(qv.y), kf3, a);
        a = fmaf(b2f_lo(qv.z), kf4, a);
        a = fmaf(b2f_hi(qv.z), kf5, a);
        a = fmaf(b2f_lo(qv.w), kf6, a);
        a = fmaf(b2f_hi(qv.w), kf7, a);
        val[r] = (mb & (1u << (g * 8 + r))) ? a * scale : -1e9f;
      }
      float m[8];
#pragma unroll
      for (int r = 0; r < 8; r++) m[r] = val[r];
#pragma unroll
      for (int off = 32; off >= 1; off >>= 1) {
#pragma unroll
        for (int r = 0; r < 8; r++) m[r] = fmaxf(m[r], __shfl_xor(m[r], off));
      }
      float ex[8], sm[8];
#pragma unroll
      for (int r = 0; r < 8; r++) { ex[r] = __expf(val[r] - m[r]); sm[r] = ex[r]; }
#pragma unroll
      for (int off = 32; off >= 1; off >>= 1) {
#pragma unroll
        for (int r = 0; r < 8; r++) sm[r] += __shfl_xor(sm[r], off);
      }
#pragma unroll
      for (int r = 0; r < 8; r++) {
        int t = tg * 16 + g * 8 + r;
        float pv = __fdividef(ex[r], sm[r]);
        pbase[t * 64 + lane] = pv;
        S[t * 68 + lane] = pv;
      }
    }
    __syncthreads();
    // ---- PV: x[t][h*8+dk] = sum_s S[t][s]*vT[h*8+dk][s]; store bf16 into dead q slice ----
    {
      const int dk = tid & 7, tr = tid >> 3;  // tr 0..31
      const float* vrow = vT + (h * 8 + dk) * 68;
      const float* s0p = S + tr * 68;
      const float* s1p = S + (tr + 32) * 68;
      float a0 = 0.f, a1 = 0.f;
#pragma unroll
      for (int s4 = 0; s4 < 16; s4++) {
        float4 v4 = *(const float4*)(vrow + s4 * 4);
        float4 sa = *(const float4*)(s0p + s4 * 4);
        float4 sb = *(const float4*)(s1p + s4 * 4);
        a0 = fmaf(sa.x, v4.x, a0); a0 = fmaf(sa.y, v4.y, a0);
        a0 = fmaf(sa.z, v4.z, a0); a0 = fmaf(sa.w, v4.w, a0);
        a1 = fmaf(sb.x, v4.x, a1); a1 = fmaf(sb.y, v4.y, a1);
        a1 = fmaf(sb.z, v4.z, a1); a1 = fmaf(sb.w, v4.w, a1);
      }
      q_b[tr * 64 + h * 8 + dk] = f2b(a0);
      q_b[(tr + 32) * 64 + h * 8 + dk] = f2b(a1);
    }
    __syncthreads();
  }

  // ---- output projection: out[t][dp] = bo[dp] + sum_c x[t][c]*Wo[dp][c] ----
  {
    float acc[16];
    float bias = bo[lane];
#pragma unroll
    for (int i = 0; i < 16; i++) acc[i] = bias;
#pragma unroll 2
    for (int c8 = 0; c8 < 8; c8++) {
      float4 wa = Wo4[(c8 * 2) * 64 + lane];
      float4 wb = Wo4[(c8 * 2 + 1) * 64 + lane];
#pragma unroll
      for (int i = 0; i < 16; i++) {
        int t = tg * 16 + i;
        uint4 xv = *(const uint4*)(q_b + t * 64 + c8 * 8);
        acc[i] = fmaf(b2f_lo(xv.x), wa.x, acc[i]);
        acc[i] = fmaf(b2f_hi(xv.x), wa.y, acc[i]);
        acc[i] = fmaf(b2f_lo(xv.y), wa.z, acc[i]);
        acc[i] = fmaf(b2f_hi(xv.y), wa.w, acc[i]);
        acc[i] = fmaf(b2f_lo(xv.z), wb.x, acc[i]);
        acc[i] = fmaf(b2f_hi(xv.z), wb.y, acc[i]);
        acc[i] = fmaf(b2f_lo(xv.w), wb.z, acc[i]);
        acc[i] = fmaf(b2f_hi(xv.w), wb.w, acc[i]);
      }
    }
#pragma unroll
    for (int i = 0; i < 16; i++)
      out[(size_t)bid * 4096 + (tg * 16 + i) * 64 + lane] = acc[i];
  }
}

extern "C" void kernel_launch(void* const* d_in, const int* in_sizes, int n_in,
                              void* d_out, int out_size, void* d_ws, size_t ws_size,
                              hipStream_t stream) {
  const float* query = (const float*)d_in[0];
  const float* key   = (const float*)d_in[1];
  const float* value = (const float*)d_in[2];
  const int*   mask  = (const int*)d_in[4];
  const float* Wq = (const float*)d_in[5];
  const float* bq = (const float*)d_in[6];
  const float* Wk = (const float*)d_in[7];
  const float* bk = (const float*)d_in[8];
  const float* Wv = (const float*)d_in[9];
  const float* bv = (const float*)d_in[10];
  const float* Wo = (const float*)d_in[11];
  const float* bo = (const float*)d_in[12];

  float* out = (float*)d_out;
  float* p_out = out + OUT_ELEMS;
  float* ws = (float*)d_ws;

  hipLaunchKernelGGL(prep_weights, dim3(128), dim3(256), 0, stream,
                     Wq, Wk, Wv, Wo, ws);
  hipLaunchKernelGGL(fused_attn, dim3(8192), dim3(256), 0, stream,
                     query, key, value, mask, ws, bq, bk, bv, bo, out, p_out);
}

// Round 4
// 321.398 us; speedup vs baseline: 5.6394x; 4.1418x over previous
//
#include <hip/hip_runtime.h>

// B=16, N=512, T=64, D=64, H=8, K=3, DK=8
// grid = 8192 blocks (one per (b,n)), 256 threads (4 waves), 3 blocks/CU
// All matmuls on MFMA 16x16x32 bf16; softmax + data movement on VALU.

#define OUT_ELEMS 33554432ull   // B*N*T*D

typedef unsigned short u16;
typedef unsigned int u32;
typedef __attribute__((ext_vector_type(8))) short short8;
typedef __attribute__((ext_vector_type(4))) float f32x4;

__device__ __forceinline__ u16 f2b(float f) {  // f32 -> bf16 RNE
  u32 u = __float_as_uint(f);
  return (u16)((u + 0x7fffu + ((u >> 16) & 1u)) >> 16);
}

// ws (ushort) layout, all in MFMA fragment order (lane l = (idx>>3)&63, elem e = idx&7):
//  wsq [0,12288):     frag f=(j*2+kk)*4+nt : Wq[d=nt*16+(l&15)][c=kk*32+(l>>4)*8+e][j]
//  wsk [12288,24576): same for Wk
//  wsv [24576,28672): frag f=w*2+kk (A-op): Wv[d=16w+(l&15)][c=kk*32+(l>>4)*8+e]
//  wso [28672,32768): frag f=kk*4+nt (B-op): Wo[dp=nt*16+(l&15)][c=kk*32+(l>>4)*8+e]
__global__ __launch_bounds__(256) void prep_weights(
    const float* __restrict__ Wq, const float* __restrict__ Wk,
    const float* __restrict__ Wv, const float* __restrict__ Wo,
    u16* __restrict__ ws) {
  int i = blockIdx.x * 256 + threadIdx.x;  // 0..32767
  int lane = (i >> 3) & 63;
  int e = i & 7;
  int m15 = lane & 15, g = lane >> 4;
  if (i < 12288) {
    int f = i >> 9;  // 0..23
    int j = f >> 3, kk = (f >> 2) & 1, nt = f & 3;
    int d = nt * 16 + m15, c = kk * 32 + g * 8 + e;
    ws[i] = f2b(Wq[(d * 64 + c) * 3 + j]);
  } else if (i < 24576) {
    int f = (i - 12288) >> 9;
    int j = f >> 3, kk = (f >> 2) & 1, nt = f & 3;
    int d = nt * 16 + m15, c = kk * 32 + g * 8 + e;
    ws[i] = f2b(Wk[(d * 64 + c) * 3 + j]);
  } else if (i < 28672) {
    int f = (i - 24576) >> 9;  // 0..7
    int w = f >> 1, kk = f & 1;
    int d = 16 * w + m15, c = kk * 32 + g * 8 + e;
    ws[i] = f2b(Wv[d * 64 + c]);
  } else if (i < 32768) {
    int f = (i - 28672) >> 9;  // 0..7
    int kk = f >> 2, nt = f & 3;
    int dp = nt * 16 + m15, c = kk * 32 + g * 8 + e;
    ws[i] = f2b(Wo[dp * 64 + c]);
  }
}

__global__ __launch_bounds__(256, 3) void fused_attn(
    const float* __restrict__ q_in, const float* __restrict__ k_in,
    const float* __restrict__ v_in, const int* __restrict__ mask,
    const u16* __restrict__ ws,
    const float* __restrict__ bq, const float* __restrict__ bk,
    const float* __restrict__ bv, const float* __restrict__ bo,
    float* __restrict__ out, float* __restrict__ p_out) {
  // LDS tiles: row pitch 72 bf16 (144B, 16B-aligned). xb rows 0,1 = zero pad.
  __shared__ __align__(16) u16 xb[66 * 72];  // staging; rows 0..63 alias pb later
  __shared__ __align__(16) u16 qb[64 * 72];  // q (scaled) [t][d]
  __shared__ __align__(16) u16 kb[64 * 72];  // k [s][d]
  __shared__ __align__(16) u16 vT[64 * 72];  // v^T [d][s]
  __shared__ __align__(16) u16 xo[64 * 72];  // attn out x [t][d]

  const int tid = threadIdx.x;
  const int bid = blockIdx.x;   // b*512 + n
  const int b = bid >> 9;
  const int l = tid & 63;
  const int w = tid >> 6;       // wave 0..3
  const int g = l >> 4;         // lane group 0..3
  const int m15 = l & 15;

  const u16* wsq = ws;
  const u16* wsk = ws + 12288;
  const u16* wsv = ws + 24576;
  const u16* wso = ws + 28672;

  const short8 z8 = {0, 0, 0, 0, 0, 0, 0, 0};

  // zero xb pad rows 0,1: 2 rows * 72 u16 = 144 u16 = 72 dwords  (R3 bug: was 36)
  if (tid < 72) ((u32*)xb)[tid] = 0u;

  // ---------- helpers as lambdas ----------
  auto stage = [&](const float* __restrict__ src) {
#pragma unroll
    for (int cc = 0; cc < 2; cc++) {
      int c = tid * 2 + cc;              // 0..511 chunks of 8 floats
      const float* p = src + c * 8;
      float4 x0 = *(const float4*)(p);
      float4 x1 = *(const float4*)(p + 4);
      u32 p0 = (u32)f2b(x0.x) | ((u32)f2b(x0.y) << 16);
      u32 p1 = (u32)f2b(x0.z) | ((u32)f2b(x0.w) << 16);
      u32 p2 = (u32)f2b(x1.x) | ((u32)f2b(x1.y) << 16);
      u32 p3 = (u32)f2b(x1.z) | ((u32)f2b(x1.w) << 16);
      int r = c >> 3, k8 = (c & 7) * 8;
      *(uint4*)(xb + (r + 2) * 72 + k8) = make_uint4(p0, p1, p2, p3);
    }
  };

  auto conv = [&](const u16* __restrict__ wpack, const float* __restrict__ bias,
                  float scale, u16* __restrict__ dst) {
    f32x4 acc[4];
#pragma unroll
    for (int nt = 0; nt < 4; nt++) {
      float bb = bias[nt * 16 + m15];
      acc[nt] = (f32x4){bb, bb, bb, bb};
    }
#pragma unroll
    for (int j = 0; j < 3; j++) {
#pragma unroll
      for (int kk = 0; kk < 2; kk++) {
        short8 a = *(const short8*)(xb + (16 * w + m15 + j) * 72 + kk * 32 + g * 8);
#pragma unroll
        for (int nt = 0; nt < 4; nt++) {
          short8 bf = *(const short8*)(wpack + (size_t)((j * 2 + kk) * 4 + nt) * 512 + l * 8);
          acc[nt] = __builtin_amdgcn_mfma_f32_16x16x32_bf16(a, bf, acc[nt], 0, 0, 0);
        }
      }
    }
#pragma unroll
    for (int nt = 0; nt < 4; nt++)
#pragma unroll
      for (int r = 0; r < 4; r++)
        dst[(16 * w + g * 4 + r) * 72 + nt * 16 + m15] = f2b(acc[nt][r] * scale);
  };

  // ---------- stage q, conv q -> qb (scale folded) ----------
  stage(q_in + (size_t)bid * 4096);
  __syncthreads();
  conv(wsq, bq, 0.35355339059327373f, qb);
  __syncthreads();

  // ---------- stage k, conv k -> kb ----------
  stage(k_in + (size_t)bid * 4096);
  __syncthreads();
  conv(wsk, bk, 1.0f, kb);
  __syncthreads();

  // ---------- stage v, v-proj -> vT[d][s] ----------
  stage(v_in + (size_t)bid * 4096);
  __syncthreads();
  {
    f32x4 acc[4];
    float bm0 = bv[16 * w + g * 4 + 0], bm1 = bv[16 * w + g * 4 + 1];
    float bm2 = bv[16 * w + g * 4 + 2], bm3 = bv[16 * w + g * 4 + 3];
#pragma unroll
    for (int nt = 0; nt < 4; nt++) acc[nt] = (f32x4){bm0, bm1, bm2, bm3};
#pragma unroll
    for (int kk = 0; kk < 2; kk++) {
      short8 a = *(const short8*)(wsv + (size_t)(w * 2 + kk) * 512 + l * 8);
#pragma unroll
      for (int nt = 0; nt < 4; nt++) {
        short8 bf = *(const short8*)(xb + (nt * 16 + m15 + 2) * 72 + kk * 32 + g * 8);
        acc[nt] = __builtin_amdgcn_mfma_f32_16x16x32_bf16(a, bf, acc[nt], 0, 0, 0);
      }
    }
#pragma unroll
    for (int nt = 0; nt < 4; nt++)
#pragma unroll
      for (int r = 0; r < 4; r++)
        vT[(16 * w + g * 4 + r) * 72 + nt * 16 + m15] = f2b(acc[nt][r]);
  }

  // mask bits: bit nt*4+r = mask[b][t=16w+g*4+r][s=nt*16+m15]
  u32 mb = 0;
#pragma unroll
  for (int nt = 0; nt < 4; nt++)
#pragma unroll
    for (int r = 0; r < 4; r++)
      if (mask[(size_t)b * 4096 + (16 * w + g * 4 + r) * 64 + nt * 16 + m15])
        mb |= 1u << (nt * 4 + r);
  __syncthreads();  // vT complete (cross-wave); xb free -> pb

  u16* pb = xb;  // P staging [t][s], rows 0..63; intra-wave use only

  // ---------- head loop: ZERO barriers (qb/pb/xo rows are wave-private; vT,kb read-only) ----------
#pragma unroll 1
  for (int h = 0; h < 8; h++) {
    // QK^T: K=8 padded to 32 (only lane-group 0 carries data)
    short8 aq = *(const short8*)(qb + (16 * w + m15) * 72 + h * 8);
    if (g != 0) aq = z8;
    f32x4 s4[4];
#pragma unroll
    for (int nt = 0; nt < 4; nt++) {
      short8 bk8 = *(const short8*)(kb + (nt * 16 + m15) * 72 + h * 8);
      if (g != 0) bk8 = z8;
      f32x4 zero = {0.f, 0.f, 0.f, 0.f};
      s4[nt] = __builtin_amdgcn_mfma_f32_16x16x32_bf16(aq, bk8, zero, 0, 0, 0);
    }
    // masked softmax over s (row = t fixed per (g,r); cols across 16 lanes x 4 nt)
    float e[4][4];
    float rs0 = 0.f, rs1 = 0.f, rs2 = 0.f, rs3 = 0.f;
#pragma unroll
    for (int nt = 0; nt < 4; nt++) {
      e[nt][0] = (mb & (1u << (nt * 4 + 0))) ? __expf(s4[nt][0]) : 0.f;
      e[nt][1] = (mb & (1u << (nt * 4 + 1))) ? __expf(s4[nt][1]) : 0.f;
      e[nt][2] = (mb & (1u << (nt * 4 + 2))) ? __expf(s4[nt][2]) : 0.f;
      e[nt][3] = (mb & (1u << (nt * 4 + 3))) ? __expf(s4[nt][3]) : 0.f;
      rs0 += e[nt][0]; rs1 += e[nt][1]; rs2 += e[nt][2]; rs3 += e[nt][3];
    }
#pragma unroll
    for (int off = 1; off <= 8; off <<= 1) {
      rs0 += __shfl_xor(rs0, off);
      rs1 += __shfl_xor(rs1, off);
      rs2 += __shfl_xor(rs2, off);
      rs3 += __shfl_xor(rs3, off);
    }
    float ri0 = __fdividef(1.f, rs0 + 1e-30f);
    float ri1 = __fdividef(1.f, rs1 + 1e-30f);
    float ri2 = __fdividef(1.f, rs2 + 1e-30f);
    float ri3 = __fdividef(1.f, rs3 + 1e-30f);
    float* pg = p_out + (((size_t)bid * 8 + h) * 4096);
#pragma unroll
    for (int nt = 0; nt < 4; nt++) {
      float p0 = e[nt][0] * ri0, p1 = e[nt][1] * ri1;
      float p2 = e[nt][2] * ri2, p3 = e[nt][3] * ri3;
      pg[(16 * w + g * 4 + 0) * 64 + nt * 16 + m15] = p0;
      pg[(16 * w + g * 4 + 1) * 64 + nt * 16 + m15] = p1;
      pg[(16 * w + g * 4 + 2) * 64 + nt * 16 + m15] = p2;
      pg[(16 * w + g * 4 + 3) * 64 + nt * 16 + m15] = p3;
      pb[(16 * w + g * 4 + 0) * 72 + nt * 16 + m15] = f2b(p0);
      pb[(16 * w + g * 4 + 1) * 72 + nt * 16 + m15] = f2b(p1);
      pb[(16 * w + g * 4 + 2) * 72 + nt * 16 + m15] = f2b(p2);
      pb[(16 * w + g * 4 + 3) * 72 + nt * 16 + m15] = f2b(p3);
    }
    // PV: x[t][h*8+dk] = sum_s P[t][s] v[s][h*8+dk]; N-cols 8..15 duplicated, discarded
    f32x4 xacc = {0.f, 0.f, 0.f, 0.f};
#pragma unroll
    for (int kk = 0; kk < 2; kk++) {
      short8 ap = *(const short8*)(pb + (16 * w + m15) * 72 + kk * 32 + g * 8);
      short8 bv8 = *(const short8*)(vT + (h * 8 + (m15 & 7)) * 72 + kk * 32 + g * 8);
      xacc = __builtin_amdgcn_mfma_f32_16x16x32_bf16(ap, bv8, xacc, 0, 0, 0);
    }
    if (m15 < 8) {
#pragma unroll
      for (int r = 0; r < 4; r++)
        xo[(16 * w + g * 4 + r) * 72 + h * 8 + m15] = f2b(xacc[r]);
    }
  }

  // ---------- output projection (xo rows are wave-private; no barrier) ----------
  {
    f32x4 acc[4];
#pragma unroll
    for (int nt = 0; nt < 4; nt++) {
      float bb = bo[nt * 16 + m15];
      acc[nt] = (f32x4){bb, bb, bb, bb};
    }
#pragma unroll
    for (int kk = 0; kk < 2; kk++) {
      short8 ax = *(const short8*)(xo + (16 * w + m15) * 72 + kk * 32 + g * 8);
#pragma unroll
      for (int nt = 0; nt < 4; nt++) {
        short8 bf = *(const short8*)(wso + (size_t)(kk * 4 + nt) * 512 + l * 8);
        acc[nt] = __builtin_amdgcn_mfma_f32_16x16x32_bf16(ax, bf, acc[nt], 0, 0, 0);
      }
    }
#pragma unroll
    for (int nt = 0; nt < 4; nt++)
#pragma unroll
      for (int r = 0; r < 4; r++)
        out[(size_t)bid * 4096 + (16 * w + g * 4 + r) * 64 + nt * 16 + m15] = acc[nt][r];
  }
}

extern "C" void kernel_launch(void* const* d_in, const int* in_sizes, int n_in,
                              void* d_out, int out_size, void* d_ws, size_t ws_size,
                              hipStream_t stream) {
  const float* query = (const float*)d_in[0];
  const float* key   = (const float*)d_in[1];
  const float* value = (const float*)d_in[2];
  const int*   mask  = (const int*)d_in[4];
  const float* Wq = (const float*)d_in[5];
  const float* bq = (const float*)d_in[6];
  const float* Wk = (const float*)d_in[7];
  const float* bk = (const float*)d_in[8];
  const float* Wv = (const float*)d_in[9];
  const float* bv = (const float*)d_in[10];
  const float* Wo = (const float*)d_in[11];
  const float* bo = (const float*)d_in[12];

  float* out = (float*)d_out;
  float* p_out = out + OUT_ELEMS;
  u16* ws = (u16*)d_ws;

  hipLaunchKernelGGL(prep_weights, dim3(128), dim3(256), 0, stream,
                     Wq, Wk, Wv, Wo, ws);
  hipLaunchKernelGGL(fused_attn, dim3(8192), dim3(256), 0, stream,
                     query, key, value, mask, ws, bq, bk, bv, bo, out, p_out);
}